// Round 8
// baseline (3086.778 us; speedup 1.0000x reference)
//
#include <hip/hip_runtime.h>

#define NB 4
#define NN 16384
#define NPT 1024
#define NS 32
#define CIN 64
#define C0 67
#define NCELL 256   // cells per batch, 64 pts each

__device__ __forceinline__ unsigned long long shfl_xor_u64(unsigned long long v, int m) {
  int lo = __shfl_xor((int)(unsigned)v, m, 64);
  int hi = __shfl_xor((int)(unsigned)(v >> 32), m, 64);
  return ((unsigned long long)(unsigned)hi << 32) | (unsigned)lo;
}

__device__ __forceinline__ int spread3(int v) {  // 4-bit value -> bits at 0,3,6,9
  return (v & 1) | ((v & 2) << 2) | ((v & 4) << 4) | ((v & 8) << 6);
}

// ---------------- Prep: Morton-bin counting sort + per-cell bbox (1 block/batch) ----
// sorted[i] = (x,y,z, orig_idx bits). Cells = 64 consecutive sorted points.
// Any valid permutation is CORRECT (bboxes computed from actual cell contents);
// the sort quality only affects pruning rate.
extern "C" __global__ __launch_bounds__(1024)
void prep_kernel(const float* __restrict__ xyz, float4* __restrict__ sorted,
                 float4* __restrict__ bbox) {
  const int b = blockIdx.x;
  const int tid = threadIdx.x;
  const int lane = tid & 63, wv = tid >> 6;   // 16 waves
  const float* base = xyz + (size_t)b * (NN * 3);
  __shared__ int hist[4096];
  __shared__ int wsum[16];
  for (int i = tid; i < 4096; i += 1024) hist[i] = 0;
  __syncthreads();
  int code[16];
#pragma unroll
  for (int i = 0; i < 16; ++i) {
    int j = i * 1024 + tid;
    float x = base[3 * j], y = base[3 * j + 1], z = base[3 * j + 2];
    int ux = min(15, max(0, (int)((x + 4.0f) * 2.0f)));
    int uy = min(15, max(0, (int)((y + 4.0f) * 2.0f)));
    int uz = min(15, max(0, (int)((z + 4.0f) * 2.0f)));
    code[i] = spread3(ux) | (spread3(uy) << 1) | (spread3(uz) << 2);
    atomicAdd(&hist[code[i]], 1);
  }
  __syncthreads();
  // exclusive scan of hist[4096]: 4 bins/thread
  int s0 = hist[4 * tid], s1 = hist[4 * tid + 1], s2 = hist[4 * tid + 2], s3 = hist[4 * tid + 3];
  int sum4 = s0 + s1 + s2 + s3;
  int incl = sum4;
#pragma unroll
  for (int off = 1; off < 64; off <<= 1) {
    int v = __shfl_up(incl, off, 64);
    if (lane >= off) incl += v;
  }
  if (lane == 63) wsum[wv] = incl;
  __syncthreads();
  int wbase = 0;
#pragma unroll
  for (int w = 0; w < 16; ++w) wbase += (w < wv) ? wsum[w] : 0;
  int excl = wbase + incl - sum4;
  __syncthreads();   // all hist reads done before overwrite
  hist[4 * tid] = excl;
  hist[4 * tid + 1] = excl + s0;
  hist[4 * tid + 2] = excl + s0 + s1;
  hist[4 * tid + 3] = excl + s0 + s1 + s2;
  __syncthreads();
  // scatter (re-read coords; within-bin order arbitrary — tie-break uses stored idx)
  float4* sb = sorted + (size_t)b * NN;
#pragma unroll
  for (int i = 0; i < 16; ++i) {
    int j = i * 1024 + tid;
    int pos = atomicAdd(&hist[code[i]], 1);
    sb[pos] = make_float4(base[3 * j], base[3 * j + 1], base[3 * j + 2], __int_as_float(j));
  }
  __syncthreads();
  // bbox per cell: wave per cell
  float4* bb = bbox + (size_t)b * (2 * NCELL);
  for (int c = wv; c < NCELL; c += 16) {
    float4 p = sb[c * 64 + lane];
    float lx = p.x, ly = p.y, lz = p.z, hx = p.x, hy = p.y, hz = p.z;
#pragma unroll
    for (int off = 32; off > 0; off >>= 1) {
      lx = fminf(lx, __shfl_xor(lx, off, 64));
      ly = fminf(ly, __shfl_xor(ly, off, 64));
      lz = fminf(lz, __shfl_xor(lz, off, 64));
      hx = fmaxf(hx, __shfl_xor(hx, off, 64));
      hy = fmaxf(hy, __shfl_xor(hy, off, 64));
      hz = fmaxf(hz, __shfl_xor(hz, off, 64));
    }
    if (lane == 0) {
      bb[2 * c] = make_float4(lx, ly, lz, 0.0f);
      bb[2 * c + 1] = make_float4(hx, hy, hz, 0.0f);
    }
  }
}

// ---------------- FPS with exact cell pruning: 1 block/batch, 512 threads ----------
// Cell cc owned by wave cc%8 at STATIC register index k=cc/8 (md[32] is the only
// loop-carried register state — no big coord arrays, no allocator fight).
// Skip cell iff dist(c,bbox)^2 > Ub*1.0001 : provably cannot change any md in it.
extern "C" __global__ __launch_bounds__(512, 1)
void fps2_kernel(const float* __restrict__ xyz, const float4* __restrict__ sorted,
                 const float4* __restrict__ bbox, float* __restrict__ newxyz) {
  const int b = blockIdx.x;
  const int tid = threadIdx.x;           // 0..511
  const int wv = tid >> 6, lane = tid & 63;
  const float* base = xyz + (size_t)b * (NN * 3);
  const float4* sb = sorted + (size_t)b * NN;
  __shared__ unsigned long long ubk[NCELL];
  __shared__ float4 bbl[NCELL], bbh[NCELL];
  __shared__ unsigned char flagb[NCELL];
  __shared__ unsigned long long part[4];
  float md[32];
#pragma unroll
  for (int k = 0; k < 32; ++k) md[k] = 1e10f;
  for (int c = tid; c < NCELL; c += 512) {
    bbl[c] = bbox[(size_t)b * (2 * NCELL) + 2 * c];
    bbh[c] = bbox[(size_t)b * (2 * NCELL) + 2 * c + 1];
    ubk[c] = ((unsigned long long)__float_as_uint(1e10f) << 32);  // arg unused: it=1 rescans all
  }
  float cx = base[0], cy = base[1], cz = base[2];
  float* onew = newxyz + (size_t)b * (NPT * 3);
  if (tid == 0) { onew[0] = cx; onew[1] = cy; onew[2] = cz; }
  __syncthreads();
  for (int it = 1; it < NPT; ++it) {
    // A1: per-cell prune test (exact-safe margin)
    if (tid < NCELL) {
      float4 lo = bbl[tid], hi = bbh[tid];
      float dxm = fmaxf(0.0f, fmaxf(lo.x - cx, cx - hi.x));
      float dym = fmaxf(0.0f, fmaxf(lo.y - cy, cy - hi.y));
      float dzm = fmaxf(0.0f, fmaxf(lo.z - cz, cz - hi.z));
      float dmin2 = dxm * dxm + dym * dym + dzm * dzm;
      float ubval = __uint_as_float((unsigned)(ubk[tid] >> 32));
      flagb[tid] = (dmin2 <= ubval * 1.0001f) ? 1 : 0;
    }
    __syncthreads();
    // A2+B: each wave rescans its flagged cells (cc = wv + 8k, static k)
    bool myf = (lane < 32) ? (flagb[wv + 8 * lane] != 0) : false;
    unsigned long long mask = __ballot(myf);   // bit k = flag of cell wv+8k (uniform)
#pragma unroll
    for (int k = 0; k < 32; ++k) {
      if ((mask >> k) & 1) {
        const int cc = wv + 8 * k;
        float4 pt = sb[cc * 64 + lane];
        // match numpy exactly: no FMA contraction, sum order (dx2+dy2)+dz2
        float dx = __fsub_rn(pt.x, cx);
        float dy = __fsub_rn(pt.y, cy);
        float dz = __fsub_rn(pt.z, cz);
        float d = __fadd_rn(__fadd_rn(__fmul_rn(dx, dx), __fmul_rn(dy, dy)), __fmul_rn(dz, dz));
        float mn = fminf(md[k], d);
        md[k] = mn;
        // d>=0: float bits monotonic; ~orig_idx breaks ties toward SMALLEST index
        unsigned long long key = ((unsigned long long)__float_as_uint(mn) << 32) |
                                 (unsigned)(~__float_as_int(pt.w));
        unsigned long long red = key;
#pragma unroll
        for (int off = 32; off > 0; off >>= 1) {
          unsigned long long o = shfl_xor_u64(red, off);
          red = (o > red) ? o : red;
        }
        if (lane == 0) ubk[cc] = red;
      }
    }
    __syncthreads();
    // C1: block argmax over 256 cell keys (waves 0-3)
    if (tid < NCELL) {
      unsigned long long red = ubk[tid];
#pragma unroll
      for (int off = 32; off > 0; off >>= 1) {
        unsigned long long o = shfl_xor_u64(red, off);
        red = (o > red) ? o : red;
      }
      if (lane == 0) part[wv] = red;
    }
    __syncthreads();
    unsigned long long g = part[0];
#pragma unroll
    for (int w = 1; w < 4; ++w) { unsigned long long o = part[w]; g = (o > g) ? o : g; }
    int j = (int)(~(unsigned)g);                     // original index
    int js = __builtin_amdgcn_readfirstlane(j);      // uniform -> scalar loads
    const float* pc = base + 3 * js;
    cx = pc[0]; cy = pc[1]; cz = pc[2];              // bit-identical source coords
    if (tid == 0) { float* o3 = onew + 3 * it; o3[0] = cx; o3[1] = cy; o3[2] = cz; }
  }
}

// ---------------- Ball query: one wave per centroid, ordered append with early exit ----------------
extern "C" __global__ __launch_bounds__(256)
void ball_kernel(const float* __restrict__ xyz, const float* __restrict__ newxyz,
                 int* __restrict__ ballidx) {
  const int lwv = threadIdx.x >> 6, lane = threadIdx.x & 63;
  const int wid = blockIdx.x * 4 + lwv;  // centroid id, 0..4095
  const int b = wid >> 10;
  const float* base = xyz + (size_t)b * (NN * 3);
  const float* c = newxyz + (size_t)wid * 3;
  float cx = c[0], cy = c[1], cz = c[2];
  float c2 = __fadd_rn(__fadd_rn(__fmul_rn(cx, cx), __fmul_rn(cy, cy)), __fmul_rn(cz, cz));
  __shared__ int list[4][NS];
  int cnt = 0;
  for (int j0 = 0; j0 < NN; j0 += 64) {
    int j = j0 + lane;
    float xx = base[3 * j + 0], xy = base[3 * j + 1], xz = base[3 * j + 2];
    float x2 = __fadd_rn(__fadd_rn(__fmul_rn(xx, xx), __fmul_rn(xy, xy)), __fmul_rn(xz, xz));
    float dt = __fadd_rn(__fadd_rn(__fmul_rn(cx, xx), __fmul_rn(cy, xy)), __fmul_rn(cz, xz));
    float d2 = __fsub_rn(__fadd_rn(c2, x2), __fmul_rn(2.0f, dt));  // (c2+x2) - 2*dot
    bool in = d2 < 0.25f;
    unsigned long long msk = __ballot(in);
    if (in) {
      int pos = cnt + (int)__popcll(msk & ((1ull << lane) - 1ull));
      if (pos < NS) list[lwv][pos] = j;
    }
    cnt += (int)__popcll(msk);
    if (cnt >= NS) break;
  }
  if (lane < NS) {
    int v;
    if (cnt == 0) v = 0;
    else v = (lane < cnt) ? list[lwv][lane] : list[lwv][0];
    ballidx[wid * NS + lane] = v;
  }
}

// ---------------- Gather + MLP(67->64->64->128) + max-pool, one block per (b,m) ----------------
extern "C" __global__ __launch_bounds__(256)
void mlp_kernel(const float* __restrict__ xyz, const float* __restrict__ feats,
                const float* __restrict__ newxyz, const int* __restrict__ ballidx,
                const float* __restrict__ W1, const float* __restrict__ b1,
                const float* __restrict__ W2, const float* __restrict__ b2,
                const float* __restrict__ W3, const float* __restrict__ b3,
                float* __restrict__ outf) {
  const int bm = blockIdx.x;
  const int b = bm >> 10, m = bm & 1023;
  const int tid = threadIdx.x;
  __align__(16) __shared__ float bufA[32 * 68];  // h0 (stride 68), then h2 (stride 64)
  __align__(16) __shared__ float bufB[32 * 64];  // h1, then partial max
  __shared__ int sidx[NS];
  if (tid < NS) sidx[tid] = ballidx[bm * NS + tid];
  const float* cb = newxyz + (size_t)bm * 3;
  float cx = cb[0], cy = cb[1], cz = cb[2];
  __syncthreads();
  // gather: 8 threads per sample
  {
    int s = tid >> 3, q = tid & 7;
    int j = sidx[s];
    float* row = bufA + s * 68;
    const float* fb = feats + (size_t)b * (CIN * NN) + j;
#pragma unroll
    for (int u = 0; u < 8; ++u) {
      int cc = (q << 3) + u;
      row[3 + cc] = fb[(size_t)cc * NN];
    }
    if (q == 0) {
      const float* p = xyz + ((size_t)b * NN + j) * 3;
      row[0] = __fsub_rn(p[0], cx);
      row[1] = __fsub_rn(p[1], cy);
      row[2] = __fsub_rn(p[2], cz);
      row[67] = 0.0f;
    }
  }
  __syncthreads();
  // layer 1: 67->64   (thread = (o, 8-sample group))
  {
    const int o = tid & 63, g = tid >> 6;
    float w[68];
    const float* wr = W1 + o * C0;
#pragma unroll
    for (int c = 0; c < C0; ++c) w[c] = wr[c];
    w[67] = 0.0f;
    float bias = b1[o];
    float acc[8];
#pragma unroll
    for (int k = 0; k < 8; ++k) acc[k] = bias;
#pragma unroll
    for (int c = 0; c < 68; c += 4) {
#pragma unroll
      for (int k = 0; k < 8; ++k) {
        float4 h = *(const float4*)(bufA + (g * 8 + k) * 68 + c);
        acc[k] = fmaf(w[c], h.x, acc[k]);
        acc[k] = fmaf(w[c + 1], h.y, acc[k]);
        acc[k] = fmaf(w[c + 2], h.z, acc[k]);
        acc[k] = fmaf(w[c + 3], h.w, acc[k]);
      }
    }
#pragma unroll
    for (int k = 0; k < 8; ++k) bufB[(g * 8 + k) * 64 + o] = fmaxf(acc[k], 0.0f);
  }
  __syncthreads();
  // layer 2: 64->64, h2 into bufA with stride 64
  {
    const int o = tid & 63, g = tid >> 6;
    float w[64];
    const float* wr = W2 + o * 64;
#pragma unroll
    for (int c = 0; c < 64; ++c) w[c] = wr[c];
    float bias = b2[o];
    float acc[8];
#pragma unroll
    for (int k = 0; k < 8; ++k) acc[k] = bias;
#pragma unroll
    for (int c = 0; c < 64; c += 4) {
#pragma unroll
      for (int k = 0; k < 8; ++k) {
        float4 h = *(const float4*)(bufB + (g * 8 + k) * 64 + c);
        acc[k] = fmaf(w[c], h.x, acc[k]);
        acc[k] = fmaf(w[c + 1], h.y, acc[k]);
        acc[k] = fmaf(w[c + 2], h.z, acc[k]);
        acc[k] = fmaf(w[c + 3], h.w, acc[k]);
      }
    }
#pragma unroll
    for (int k = 0; k < 8; ++k) bufA[(g * 8 + k) * 64 + o] = fmaxf(acc[k], 0.0f);
  }
  __syncthreads();
  // layer 3: 64->128 (thread = (o128, 16-sample group)), fused relu+max
  {
    const int o = tid & 127, g = tid >> 7;
    float w[64];
    const float* wr = W3 + o * 64;
#pragma unroll
    for (int c = 0; c < 64; ++c) w[c] = wr[c];
    float bias = b3[o];
    float acc[16];
#pragma unroll
    for (int k = 0; k < 16; ++k) acc[k] = bias;
#pragma unroll
    for (int kb = 0; kb < 16; kb += 8) {   // 8-sample sub-blocks to limit live registers
#pragma unroll
      for (int c = 0; c < 64; c += 4) {
#pragma unroll
        for (int k = 0; k < 8; ++k) {
          float4 h = *(const float4*)(bufA + (g * 16 + kb + k) * 64 + c);
          acc[kb + k] = fmaf(w[c], h.x, acc[kb + k]);
          acc[kb + k] = fmaf(w[c + 1], h.y, acc[kb + k]);
          acc[kb + k] = fmaf(w[c + 2], h.z, acc[kb + k]);
          acc[kb + k] = fmaf(w[c + 3], h.w, acc[kb + k]);
        }
      }
    }
    float mx = 0.0f;
#pragma unroll
    for (int k = 0; k < 16; ++k) mx = fmaxf(mx, fmaxf(acc[k], 0.0f));
    bufB[g * 128 + o] = mx;
  }
  __syncthreads();
  if (tid < 128) {
    float v = fmaxf(bufB[tid], bufB[128 + tid]);
    outf[((size_t)b * 128 + tid) * NPT + m] = v;
  }
}

extern "C" void kernel_launch(void* const* d_in, const int* in_sizes, int n_in,
                              void* d_out, int out_size, void* d_ws, size_t ws_size,
                              hipStream_t stream) {
  const float* xyz   = (const float*)d_in[0];
  const float* feats = (const float*)d_in[1];
  const float* W1 = (const float*)d_in[2];
  const float* b1 = (const float*)d_in[3];
  const float* W2 = (const float*)d_in[4];
  const float* b2 = (const float*)d_in[5];
  const float* W3 = (const float*)d_in[6];
  const float* b3 = (const float*)d_in[7];
  float* out = (float*)d_out;
  float* newxyz = out;                 // (4,1024,3)
  float* outf = out + NB * NPT * 3;    // (4,128,1024)
  // ws layout: sorted float4[4*16384] (1MB) | bbox float4[4*512] (32KB) | ballidx (512KB)
  float4* sorted = (float4*)d_ws;
  float4* bbox = sorted + (size_t)NB * NN;
  int* ballidx = (int*)(bbox + (size_t)NB * 2 * NCELL);

  hipLaunchKernelGGL(prep_kernel, dim3(NB), dim3(1024), 0, stream, xyz, sorted, bbox);
  hipLaunchKernelGGL(fps2_kernel, dim3(NB), dim3(512), 0, stream, xyz, sorted, bbox, newxyz);
  hipLaunchKernelGGL(ball_kernel, dim3(NB * NPT / 4), dim3(256), 0, stream, xyz, newxyz, ballidx);
  hipLaunchKernelGGL(mlp_kernel, dim3(NB * NPT), dim3(256), 0, stream,
                     xyz, feats, newxyz, ballidx, W1, b1, W2, b2, W3, b3, outf);
}

// Round 9
// 2246.775 us; speedup vs baseline: 1.3739x; 1.3739x over previous
//
#include <hip/hip_runtime.h>

#define NB 4
#define NN 16384
#define NPT 1024
#define NS 32
#define CIN 64
#define C0 67

__device__ __forceinline__ unsigned long long shfl_xor_u64(unsigned long long v, int m) {
  int lo = __shfl_xor((int)(unsigned)v, m, 64);
  int hi = __shfl_xor((int)(unsigned)(v >> 32), m, 64);
  return ((unsigned long long)(unsigned)hi << 32) | (unsigned)lo;
}

#define REP32(M) M(0) M(1) M(2) M(3) M(4) M(5) M(6) M(7) M(8) M(9) M(10) M(11) \
  M(12) M(13) M(14) M(15) M(16) M(17) M(18) M(19) M(20) M(21) M(22) M(23) \
  M(24) M(25) M(26) M(27) M(28) M(29) M(30) M(31)

// ---------------- FPS: one block per batch, 512 threads, 32 pts/thread ----------------
// Rounds 3-8 lesson: the register allocator refuses to keep >~96 arch VGPRs live
// (it remats the loop-invariant coords from L2 every iteration, ~0.8us/iter hidden
// traffic; attributes/pins don't change it). Fix: park the 96 coord values in the
// AGPR half of gfx950's unified 512-reg file via explicit v_accvgpr_write/read
// ("a" asm constraints, static names). volatile => not hoistable/rematerializable;
// AGPR pressure 96 << 256 => never spilled. VGPRs hold only md[32]+working (~72).
extern "C" __global__ __attribute__((amdgpu_waves_per_eu(2, 2))) __launch_bounds__(512)
void fps_kernel(const float* __restrict__ xyz, float* __restrict__ newxyz) {
  const int b = blockIdx.x;
  const int tid = threadIdx.x;          // 0..511
  const int wv = tid >> 6, lane = tid & 63;
  const float* base = xyz + (size_t)b * (NN * 3);

#define DECLA(K) float ax##K, ay##K, az##K;
  REP32(DECLA)
#undef DECLA

#define LOADA(K) { int j = (K * 512) + tid; \
    float x_ = base[3 * j], y_ = base[3 * j + 1], z_ = base[3 * j + 2]; \
    asm volatile("v_accvgpr_write_b32 %0, %1" : "=a"(ax##K) : "v"(x_)); \
    asm volatile("v_accvgpr_write_b32 %0, %1" : "=a"(ay##K) : "v"(y_)); \
    asm volatile("v_accvgpr_write_b32 %0, %1" : "=a"(az##K) : "v"(z_)); }
  REP32(LOADA)
#undef LOADA

  float md[32];
#pragma unroll
  for (int k = 0; k < 32; ++k) md[k] = 1e10f;

  __shared__ unsigned long long part[2][8];  // parity-double-buffered wave-winner keys
  float* onew = newxyz + (size_t)b * (NPT * 3);
  // iteration 0: centroid = point 0 (broadcast load)
  float cx = base[0], cy = base[1], cz = base[2];
  if (tid == 0) { onew[0] = cx; onew[1] = cy; onew[2] = cz; }

  for (int it = 1; it < NPT; ++it) {
    const int p = it & 1;
    float bestv = -1.0f; int bestk = 0;
    // match numpy exactly: no FMA contraction, sum order (dx2+dy2)+dz2;
    // strict > keeps earliest k (lowest j in-thread)
#define FPS_STEP(K) { float x_, y_, z_; \
    asm volatile("v_accvgpr_read_b32 %0, %1" : "=v"(x_) : "a"(ax##K)); \
    asm volatile("v_accvgpr_read_b32 %0, %1" : "=v"(y_) : "a"(ay##K)); \
    asm volatile("v_accvgpr_read_b32 %0, %1" : "=v"(z_) : "a"(az##K)); \
    float dx_ = __fsub_rn(x_, cx), dy_ = __fsub_rn(y_, cy), dz_ = __fsub_rn(z_, cz); \
    float d_ = __fadd_rn(__fadd_rn(__fmul_rn(dx_, dx_), __fmul_rn(dy_, dy_)), __fmul_rn(dz_, dz_)); \
    float mn_ = fminf(md[K], d_); md[K] = mn_; \
    bool gt_ = mn_ > bestv; bestv = gt_ ? mn_ : bestv; bestk = gt_ ? K : bestk; }
    REP32(FPS_STEP)
#undef FPS_STEP
    int bestj = (bestk << 9) + tid;
    // d>=0 so float bits are monotonic; ~idx breaks ties toward the SMALLEST index
    unsigned long long key = ((unsigned long long)__float_as_uint(bestv) << 32) | (unsigned)(~bestj);
    unsigned long long red = key;
#pragma unroll
    for (int off = 32; off > 0; off >>= 1) {
      unsigned long long o = shfl_xor_u64(red, off);
      red = (o > red) ? o : red;
    }
    if (lane == 0) part[p][wv] = red;
    __syncthreads();
    // every thread combines the 8 wave winners locally (broadcast LDS reads)
    unsigned long long g = part[p][0];
#pragma unroll
    for (int w = 1; w < 8; ++w) {
      unsigned long long o = part[p][w];
      g = (o > g) ? o : g;
    }
    int j = (int)(~(unsigned)g);
    int js = __builtin_amdgcn_readfirstlane(j);      // uniform -> scalar loads
    const float* pc = base + 3 * js;
    cx = pc[0]; cy = pc[1]; cz = pc[2];              // bit-identical to source coords
    if (tid == 0) { float* o3 = onew + 3 * it; o3[0] = cx; o3[1] = cy; o3[2] = cz; }
    // no second barrier: next iteration writes the OTHER parity's cells
  }
}

// ---------------- Ball query: one wave per centroid, ordered append with early exit ----------------
extern "C" __global__ __launch_bounds__(256)
void ball_kernel(const float* __restrict__ xyz, const float* __restrict__ newxyz,
                 int* __restrict__ ballidx) {
  const int lwv = threadIdx.x >> 6, lane = threadIdx.x & 63;
  const int wid = blockIdx.x * 4 + lwv;  // centroid id, 0..4095
  const int b = wid >> 10;
  const float* base = xyz + (size_t)b * (NN * 3);
  const float* c = newxyz + (size_t)wid * 3;
  float cx = c[0], cy = c[1], cz = c[2];
  float c2 = __fadd_rn(__fadd_rn(__fmul_rn(cx, cx), __fmul_rn(cy, cy)), __fmul_rn(cz, cz));
  __shared__ int list[4][NS];
  int cnt = 0;
  for (int j0 = 0; j0 < NN; j0 += 64) {
    int j = j0 + lane;
    float xx = base[3 * j + 0], xy = base[3 * j + 1], xz = base[3 * j + 2];
    float x2 = __fadd_rn(__fadd_rn(__fmul_rn(xx, xx), __fmul_rn(xy, xy)), __fmul_rn(xz, xz));
    float dt = __fadd_rn(__fadd_rn(__fmul_rn(cx, xx), __fmul_rn(cy, xy)), __fmul_rn(cz, xz));
    float d2 = __fsub_rn(__fadd_rn(c2, x2), __fmul_rn(2.0f, dt));  // (c2+x2) - 2*dot
    bool in = d2 < 0.25f;
    unsigned long long msk = __ballot(in);
    if (in) {
      int pos = cnt + (int)__popcll(msk & ((1ull << lane) - 1ull));
      if (pos < NS) list[lwv][pos] = j;
    }
    cnt += (int)__popcll(msk);
    if (cnt >= NS) break;
  }
  if (lane < NS) {
    int v;
    if (cnt == 0) v = 0;
    else v = (lane < cnt) ? list[lwv][lane] : list[lwv][0];
    ballidx[wid * NS + lane] = v;
  }
}

// ---------------- Gather + MLP(67->64->64->128) + max-pool, one block per (b,m) ----------------
extern "C" __global__ __launch_bounds__(256)
void mlp_kernel(const float* __restrict__ xyz, const float* __restrict__ feats,
                const float* __restrict__ newxyz, const int* __restrict__ ballidx,
                const float* __restrict__ W1, const float* __restrict__ b1,
                const float* __restrict__ W2, const float* __restrict__ b2,
                const float* __restrict__ W3, const float* __restrict__ b3,
                float* __restrict__ outf) {
  const int bm = blockIdx.x;
  const int b = bm >> 10, m = bm & 1023;
  const int tid = threadIdx.x;
  __align__(16) __shared__ float bufA[32 * 68];  // h0 (stride 68), then h2 (stride 64)
  __align__(16) __shared__ float bufB[32 * 64];  // h1, then partial max
  __shared__ int sidx[NS];
  if (tid < NS) sidx[tid] = ballidx[bm * NS + tid];
  const float* cb = newxyz + (size_t)bm * 3;
  float cx = cb[0], cy = cb[1], cz = cb[2];
  __syncthreads();
  // gather: 8 threads per sample
  {
    int s = tid >> 3, q = tid & 7;
    int j = sidx[s];
    float* row = bufA + s * 68;
    const float* fb = feats + (size_t)b * (CIN * NN) + j;
#pragma unroll
    for (int u = 0; u < 8; ++u) {
      int cc = (q << 3) + u;
      row[3 + cc] = fb[(size_t)cc * NN];
    }
    if (q == 0) {
      const float* p = xyz + ((size_t)b * NN + j) * 3;
      row[0] = __fsub_rn(p[0], cx);
      row[1] = __fsub_rn(p[1], cy);
      row[2] = __fsub_rn(p[2], cz);
      row[67] = 0.0f;
    }
  }
  __syncthreads();
  // layer 1: 67->64   (thread = (o, 8-sample group))
  {
    const int o = tid & 63, g = tid >> 6;
    float w[68];
    const float* wr = W1 + o * C0;
#pragma unroll
    for (int c = 0; c < C0; ++c) w[c] = wr[c];
    w[67] = 0.0f;
    float bias = b1[o];
    float acc[8];
#pragma unroll
    for (int k = 0; k < 8; ++k) acc[k] = bias;
#pragma unroll
    for (int c = 0; c < 68; c += 4) {
#pragma unroll
      for (int k = 0; k < 8; ++k) {
        float4 h = *(const float4*)(bufA + (g * 8 + k) * 68 + c);
        acc[k] = fmaf(w[c], h.x, acc[k]);
        acc[k] = fmaf(w[c + 1], h.y, acc[k]);
        acc[k] = fmaf(w[c + 2], h.z, acc[k]);
        acc[k] = fmaf(w[c + 3], h.w, acc[k]);
      }
    }
#pragma unroll
    for (int k = 0; k < 8; ++k) bufB[(g * 8 + k) * 64 + o] = fmaxf(acc[k], 0.0f);
  }
  __syncthreads();
  // layer 2: 64->64, h2 into bufA with stride 64
  {
    const int o = tid & 63, g = tid >> 6;
    float w[64];
    const float* wr = W2 + o * 64;
#pragma unroll
    for (int c = 0; c < 64; ++c) w[c] = wr[c];
    float bias = b2[o];
    float acc[8];
#pragma unroll
    for (int k = 0; k < 8; ++k) acc[k] = bias;
#pragma unroll
    for (int c = 0; c < 64; c += 4) {
#pragma unroll
      for (int k = 0; k < 8; ++k) {
        float4 h = *(const float4*)(bufB + (g * 8 + k) * 64 + c);
        acc[k] = fmaf(w[c], h.x, acc[k]);
        acc[k] = fmaf(w[c + 1], h.y, acc[k]);
        acc[k] = fmaf(w[c + 2], h.z, acc[k]);
        acc[k] = fmaf(w[c + 3], h.w, acc[k]);
      }
    }
#pragma unroll
    for (int k = 0; k < 8; ++k) bufA[(g * 8 + k) * 64 + o] = fmaxf(acc[k], 0.0f);
  }
  __syncthreads();
  // layer 3: 64->128 (thread = (o128, 16-sample group)), fused relu+max
  {
    const int o = tid & 127, g = tid >> 7;
    float w[64];
    const float* wr = W3 + o * 64;
#pragma unroll
    for (int c = 0; c < 64; ++c) w[c] = wr[c];
    float bias = b3[o];
    float acc[16];
#pragma unroll
    for (int k = 0; k < 16; ++k) acc[k] = bias;
#pragma unroll
    for (int kb = 0; kb < 16; kb += 8) {   // 8-sample sub-blocks to limit live registers
#pragma unroll
      for (int c = 0; c < 64; c += 4) {
#pragma unroll
        for (int k = 0; k < 8; ++k) {
          float4 h = *(const float4*)(bufA + (g * 16 + kb + k) * 64 + c);
          acc[kb + k] = fmaf(w[c], h.x, acc[kb + k]);
          acc[kb + k] = fmaf(w[c + 1], h.y, acc[kb + k]);
          acc[kb + k] = fmaf(w[c + 2], h.z, acc[kb + k]);
          acc[kb + k] = fmaf(w[c + 3], h.w, acc[kb + k]);
        }
      }
    }
    float mx = 0.0f;
#pragma unroll
    for (int k = 0; k < 16; ++k) mx = fmaxf(mx, fmaxf(acc[k], 0.0f));
    bufB[g * 128 + o] = mx;
  }
  __syncthreads();
  if (tid < 128) {
    float v = fmaxf(bufB[tid], bufB[128 + tid]);
    outf[((size_t)b * 128 + tid) * NPT + m] = v;
  }
}

extern "C" void kernel_launch(void* const* d_in, const int* in_sizes, int n_in,
                              void* d_out, int out_size, void* d_ws, size_t ws_size,
                              hipStream_t stream) {
  const float* xyz   = (const float*)d_in[0];
  const float* feats = (const float*)d_in[1];
  const float* W1 = (const float*)d_in[2];
  const float* b1 = (const float*)d_in[3];
  const float* W2 = (const float*)d_in[4];
  const float* b2 = (const float*)d_in[5];
  const float* W3 = (const float*)d_in[6];
  const float* b3 = (const float*)d_in[7];
  float* out = (float*)d_out;
  float* newxyz = out;                 // (4,1024,3)
  float* outf = out + NB * NPT * 3;    // (4,128,1024)
  int* ballidx = (int*)d_ws;           // 4096*32 ints

  hipLaunchKernelGGL(fps_kernel, dim3(NB), dim3(512), 0, stream, xyz, newxyz);
  hipLaunchKernelGGL(ball_kernel, dim3(NB * NPT / 4), dim3(256), 0, stream, xyz, newxyz, ballidx);
  hipLaunchKernelGGL(mlp_kernel, dim3(NB * NPT), dim3(256), 0, stream,
                     xyz, feats, newxyz, ballidx, W1, b1, W2, b2, W3, b3, outf);
}

// Round 10
// 2142.190 us; speedup vs baseline: 1.4409x; 1.0488x over previous
//
#include <hip/hip_runtime.h>

#define NB 4
#define NN 16384
#define NPT 1024
#define NS 32
#define CIN 64
#define C0 67
#define NCELL 256   // sorted chunks per batch, 64 pts each

__device__ __forceinline__ unsigned long long shfl_xor_u64(unsigned long long v, int m) {
  int lo = __shfl_xor((int)(unsigned)v, m, 64);
  int hi = __shfl_xor((int)(unsigned)(v >> 32), m, 64);
  return ((unsigned long long)(unsigned)hi << 32) | (unsigned)lo;
}

__device__ __forceinline__ int spread3(int v) {  // 4-bit value -> bits at 0,3,6,9
  return (v & 1) | ((v & 2) << 2) | ((v & 4) << 4) | ((v & 8) << 6);
}

#define REP32(M) M(0) M(1) M(2) M(3) M(4) M(5) M(6) M(7) M(8) M(9) M(10) M(11) \
  M(12) M(13) M(14) M(15) M(16) M(17) M(18) M(19) M(20) M(21) M(22) M(23) \
  M(24) M(25) M(26) M(27) M(28) M(29) M(30) M(31)

// ---------------- Prep: Morton-bin counting sort + per-chunk bbox (1 block/batch) ----
// sorted[i] = (x,y,z, ~orig_idx bits). Chunks = 64 consecutive sorted points.
// Any permutation is CORRECT (bboxes from actual contents); sort only affects prune rate.
extern "C" __global__ __launch_bounds__(1024)
void prep_kernel(const float* __restrict__ xyz, float4* __restrict__ sorted,
                 float4* __restrict__ bbox) {
  const int b = blockIdx.x;
  const int tid = threadIdx.x;
  const int lane = tid & 63, wv = tid >> 6;   // 16 waves
  const float* base = xyz + (size_t)b * (NN * 3);
  __shared__ int hist[4096];
  __shared__ int wsum[16];
  for (int i = tid; i < 4096; i += 1024) hist[i] = 0;
  __syncthreads();
  int code[16];
#pragma unroll
  for (int i = 0; i < 16; ++i) {
    int j = i * 1024 + tid;
    float x = base[3 * j], y = base[3 * j + 1], z = base[3 * j + 2];
    int ux = min(15, max(0, (int)((x + 4.0f) * 2.0f)));
    int uy = min(15, max(0, (int)((y + 4.0f) * 2.0f)));
    int uz = min(15, max(0, (int)((z + 4.0f) * 2.0f)));
    code[i] = spread3(ux) | (spread3(uy) << 1) | (spread3(uz) << 2);
    atomicAdd(&hist[code[i]], 1);
  }
  __syncthreads();
  int s0 = hist[4 * tid], s1 = hist[4 * tid + 1], s2 = hist[4 * tid + 2], s3 = hist[4 * tid + 3];
  int sum4 = s0 + s1 + s2 + s3;
  int incl = sum4;
#pragma unroll
  for (int off = 1; off < 64; off <<= 1) {
    int v = __shfl_up(incl, off, 64);
    if (lane >= off) incl += v;
  }
  if (lane == 63) wsum[wv] = incl;
  __syncthreads();
  int wbase = 0;
#pragma unroll
  for (int w = 0; w < 16; ++w) wbase += (w < wv) ? wsum[w] : 0;
  int excl = wbase + incl - sum4;
  __syncthreads();
  hist[4 * tid] = excl;
  hist[4 * tid + 1] = excl + s0;
  hist[4 * tid + 2] = excl + s0 + s1;
  hist[4 * tid + 3] = excl + s0 + s1 + s2;
  __syncthreads();
  float4* sb = sorted + (size_t)b * NN;
#pragma unroll
  for (int i = 0; i < 16; ++i) {
    int j = i * 1024 + tid;
    int pos = atomicAdd(&hist[code[i]], 1);
    sb[pos] = make_float4(base[3 * j], base[3 * j + 1], base[3 * j + 2],
                          __uint_as_float(~(unsigned)j));
  }
  __syncthreads();
  float4* bb = bbox + (size_t)b * (2 * NCELL);
  for (int c = wv; c < NCELL; c += 16) {
    float4 p = sb[c * 64 + lane];
    float lx = p.x, ly = p.y, lz = p.z, hx = p.x, hy = p.y, hz = p.z;
#pragma unroll
    for (int off = 32; off > 0; off >>= 1) {
      lx = fminf(lx, __shfl_xor(lx, off, 64));
      ly = fminf(ly, __shfl_xor(ly, off, 64));
      lz = fminf(lz, __shfl_xor(lz, off, 64));
      hx = fmaxf(hx, __shfl_xor(hx, off, 64));
      hy = fmaxf(hy, __shfl_xor(hy, off, 64));
      hz = fmaxf(hz, __shfl_xor(hz, off, 64));
    }
    if (lane == 0) {
      bb[2 * c] = make_float4(lx, ly, lz, 0.0f);
      bb[2 * c + 1] = make_float4(hx, hy, hz, 0.0f);
    }
  }
}

// ---------------- FPS: pruned brute force, 512 threads, AGPR-resident coords ----------
// Thread t slot k = sorted point k*512+t; (wave w, slot k) = chunk w+8k exactly.
// Lane L of wave w owns chunk w+8L's bbox+Ub in static lane registers.
// Ub maintenance is O(1): Ub = min(Ub, farCorner^2(c,bbox)) when rescanned (valid since
// max_i min(a_i,b_i) <= min(max a_i, max b_i)). Skip iff minCorner^2 > Ub*1.0001 —
// provably cannot change any md in the chunk (margin >> 4-ulp rounding of both sides).
// ONE wave reduce per iteration (round 8's per-chunk reduces were the regression).
extern "C" __global__ __attribute__((amdgpu_waves_per_eu(2, 2))) __launch_bounds__(512)
void fps_kernel(const float* __restrict__ xyz, const float4* __restrict__ sorted,
                const float4* __restrict__ bbox, float* __restrict__ newxyz) {
  const int b = blockIdx.x;
  const int tid = threadIdx.x;          // 0..511
  const int wv = tid >> 6, lane = tid & 63;
  const float* base = xyz + (size_t)b * (NN * 3);
  const float4* sb = sorted + (size_t)b * NN;

#define DECLA(K) float ax##K, ay##K, az##K; unsigned ai##K;
  REP32(DECLA)
#undef DECLA

#define LOADA(K) { float4 pt = sb[(K * 512) + tid]; unsigned ni_ = __float_as_uint(pt.w); \
    asm volatile("v_accvgpr_write_b32 %0, %1" : "=a"(ax##K) : "v"(pt.x)); \
    asm volatile("v_accvgpr_write_b32 %0, %1" : "=a"(ay##K) : "v"(pt.y)); \
    asm volatile("v_accvgpr_write_b32 %0, %1" : "=a"(az##K) : "v"(pt.z)); \
    asm volatile("v_accvgpr_write_b32 %0, %1" : "=a"(ai##K) : "v"(ni_)); }
  REP32(LOADA)
#undef LOADA

  float md[32];
#pragma unroll
  for (int k = 0; k < 32; ++k) md[k] = 1e10f;

  // lane L (<32) of wave w owns chunk w+8L: bbox + Ub in static lane registers
  float blx, bly, blz, bhx, bhy, bhz, Ub = 1e10f;
  if (lane < 32) {
    const float4* bbp = bbox + (size_t)b * (2 * NCELL) + 2 * (wv + 8 * lane);
    float4 lo = bbp[0], hi = bbp[1];
    blx = lo.x; bly = lo.y; blz = lo.z; bhx = hi.x; bhy = hi.y; bhz = hi.z;
  } else {  // never matches: minc2 = +huge
    blx = bly = blz = 1e30f; bhx = bhy = bhz = 1e30f;
  }

  __shared__ unsigned long long part[2][8];
  float* onew = newxyz + (size_t)b * (NPT * 3);
  float cx = base[0], cy = base[1], cz = base[2];   // centroid 0 = original point 0
  if (tid == 0) { onew[0] = cx; onew[1] = cy; onew[2] = cz; }

  for (int it = 1; it < NPT; ++it) {
    const int p = it & 1;
    // --- prune test (lane L decides chunk w+8L) + O(1) Ub tighten ---
    float dxm = fmaxf(0.0f, fmaxf(blx - cx, cx - bhx));
    float dym = fmaxf(0.0f, fmaxf(bly - cy, cy - bhy));
    float dzm = fmaxf(0.0f, fmaxf(blz - cz, cz - bhz));
    float minc2 = dxm * dxm + dym * dym + dzm * dzm;
    bool myf = (lane < 32) && (minc2 <= Ub * 1.0001f);
    if (myf) {
      float fdx = fmaxf(cx - blx, bhx - cx);
      float fdy = fmaxf(cy - bly, bhy - cy);
      float fdz = fmaxf(cz - blz, bhz - cz);
      Ub = fminf(Ub, fdx * fdx + fdy * fdy + fdz * fdz);
    }
    unsigned long long mask = __ballot(myf);   // bit L = rescan chunk w+8L (wave-uniform)

    // --- rescan flagged chunks only (bit K gates slot K) ---
    // match numpy exactly: no FMA contraction, sum order (dx2+dy2)+dz2
#define RESCAN(K) if (mask & (1ull << K)) { float x_, y_, z_; \
    asm volatile("v_accvgpr_read_b32 %0, %1" : "=v"(x_) : "a"(ax##K)); \
    asm volatile("v_accvgpr_read_b32 %0, %1" : "=v"(y_) : "a"(ay##K)); \
    asm volatile("v_accvgpr_read_b32 %0, %1" : "=v"(z_) : "a"(az##K)); \
    float dx_ = __fsub_rn(x_, cx), dy_ = __fsub_rn(y_, cy), dz_ = __fsub_rn(z_, cz); \
    float d_ = __fadd_rn(__fadd_rn(__fmul_rn(dx_, dx_), __fmul_rn(dy_, dy_)), __fmul_rn(dz_, dz_)); \
    md[K] = fminf(md[K], d_); }
    REP32(RESCAN)
#undef RESCAN

    // --- full scan: exact u64 key (md_bits:~idx), ties -> smallest original index ---
    unsigned long long bestkey = 0ull;
#define SCAN(K) { unsigned ni_; \
    asm volatile("v_accvgpr_read_b32 %0, %1" : "=v"(ni_) : "a"(ai##K)); \
    unsigned long long key_ = (((unsigned long long)__float_as_uint(md[K])) << 32) | ni_; \
    bestkey = (key_ > bestkey) ? key_ : bestkey; }
    REP32(SCAN)
#undef SCAN

    unsigned long long red = bestkey;
#pragma unroll
    for (int off = 32; off > 0; off >>= 1) {
      unsigned long long o = shfl_xor_u64(red, off);
      red = (o > red) ? o : red;
    }
    if (lane == 0) part[p][wv] = red;
    __syncthreads();
    unsigned long long g = part[p][0];
#pragma unroll
    for (int w = 1; w < 8; ++w) {
      unsigned long long o = part[p][w];
      g = (o > g) ? o : g;
    }
    int j = (int)(~(unsigned)g);                     // original index of winner
    int js = __builtin_amdgcn_readfirstlane(j);      // uniform -> scalar loads
    const float* pc = base + 3 * js;
    cx = pc[0]; cy = pc[1]; cz = pc[2];              // bit-identical source coords
    if (tid == 0) { float* o3 = onew + 3 * it; o3[0] = cx; o3[1] = cy; o3[2] = cz; }
  }
}

// ---------------- Ball query: one wave per centroid, ordered append with early exit ----------------
extern "C" __global__ __launch_bounds__(256)
void ball_kernel(const float* __restrict__ xyz, const float* __restrict__ newxyz,
                 int* __restrict__ ballidx) {
  const int lwv = threadIdx.x >> 6, lane = threadIdx.x & 63;
  const int wid = blockIdx.x * 4 + lwv;  // centroid id, 0..4095
  const int b = wid >> 10;
  const float* base = xyz + (size_t)b * (NN * 3);
  const float* c = newxyz + (size_t)wid * 3;
  float cx = c[0], cy = c[1], cz = c[2];
  float c2 = __fadd_rn(__fadd_rn(__fmul_rn(cx, cx), __fmul_rn(cy, cy)), __fmul_rn(cz, cz));
  __shared__ int list[4][NS];
  int cnt = 0;
  for (int j0 = 0; j0 < NN; j0 += 64) {
    int j = j0 + lane;
    float xx = base[3 * j + 0], xy = base[3 * j + 1], xz = base[3 * j + 2];
    float x2 = __fadd_rn(__fadd_rn(__fmul_rn(xx, xx), __fmul_rn(xy, xy)), __fmul_rn(xz, xz));
    float dt = __fadd_rn(__fadd_rn(__fmul_rn(cx, xx), __fmul_rn(cy, xy)), __fmul_rn(cz, xz));
    float d2 = __fsub_rn(__fadd_rn(c2, x2), __fmul_rn(2.0f, dt));  // (c2+x2) - 2*dot
    bool in = d2 < 0.25f;
    unsigned long long msk = __ballot(in);
    if (in) {
      int pos = cnt + (int)__popcll(msk & ((1ull << lane) - 1ull));
      if (pos < NS) list[lwv][pos] = j;
    }
    cnt += (int)__popcll(msk);
    if (cnt >= NS) break;
  }
  if (lane < NS) {
    int v;
    if (cnt == 0) v = 0;
    else v = (lane < cnt) ? list[lwv][lane] : list[lwv][0];
    ballidx[wid * NS + lane] = v;
  }
}

// ---------------- Gather + MLP(67->64->64->128) + max-pool, one block per (b,m) ----------------
extern "C" __global__ __launch_bounds__(256)
void mlp_kernel(const float* __restrict__ xyz, const float* __restrict__ feats,
                const float* __restrict__ newxyz, const int* __restrict__ ballidx,
                const float* __restrict__ W1, const float* __restrict__ b1,
                const float* __restrict__ W2, const float* __restrict__ b2,
                const float* __restrict__ W3, const float* __restrict__ b3,
                float* __restrict__ outf) {
  const int bm = blockIdx.x;
  const int b = bm >> 10, m = bm & 1023;
  const int tid = threadIdx.x;
  __align__(16) __shared__ float bufA[32 * 68];
  __align__(16) __shared__ float bufB[32 * 64];
  __shared__ int sidx[NS];
  if (tid < NS) sidx[tid] = ballidx[bm * NS + tid];
  const float* cb = newxyz + (size_t)bm * 3;
  float cx = cb[0], cy = cb[1], cz = cb[2];
  __syncthreads();
  {
    int s = tid >> 3, q = tid & 7;
    int j = sidx[s];
    float* row = bufA + s * 68;
    const float* fb = feats + (size_t)b * (CIN * NN) + j;
#pragma unroll
    for (int u = 0; u < 8; ++u) {
      int cc = (q << 3) + u;
      row[3 + cc] = fb[(size_t)cc * NN];
    }
    if (q == 0) {
      const float* p = xyz + ((size_t)b * NN + j) * 3;
      row[0] = __fsub_rn(p[0], cx);
      row[1] = __fsub_rn(p[1], cy);
      row[2] = __fsub_rn(p[2], cz);
      row[67] = 0.0f;
    }
  }
  __syncthreads();
  {
    const int o = tid & 63, g = tid >> 6;
    float w[68];
    const float* wr = W1 + o * C0;
#pragma unroll
    for (int c = 0; c < C0; ++c) w[c] = wr[c];
    w[67] = 0.0f;
    float bias = b1[o];
    float acc[8];
#pragma unroll
    for (int k = 0; k < 8; ++k) acc[k] = bias;
#pragma unroll
    for (int c = 0; c < 68; c += 4) {
#pragma unroll
      for (int k = 0; k < 8; ++k) {
        float4 h = *(const float4*)(bufA + (g * 8 + k) * 68 + c);
        acc[k] = fmaf(w[c], h.x, acc[k]);
        acc[k] = fmaf(w[c + 1], h.y, acc[k]);
        acc[k] = fmaf(w[c + 2], h.z, acc[k]);
        acc[k] = fmaf(w[c + 3], h.w, acc[k]);
      }
    }
#pragma unroll
    for (int k = 0; k < 8; ++k) bufB[(g * 8 + k) * 64 + o] = fmaxf(acc[k], 0.0f);
  }
  __syncthreads();
  {
    const int o = tid & 63, g = tid >> 6;
    float w[64];
    const float* wr = W2 + o * 64;
#pragma unroll
    for (int c = 0; c < 64; ++c) w[c] = wr[c];
    float bias = b2[o];
    float acc[8];
#pragma unroll
    for (int k = 0; k < 8; ++k) acc[k] = bias;
#pragma unroll
    for (int c = 0; c < 64; c += 4) {
#pragma unroll
      for (int k = 0; k < 8; ++k) {
        float4 h = *(const float4*)(bufB + (g * 8 + k) * 64 + c);
        acc[k] = fmaf(w[c], h.x, acc[k]);
        acc[k] = fmaf(w[c + 1], h.y, acc[k]);
        acc[k] = fmaf(w[c + 2], h.z, acc[k]);
        acc[k] = fmaf(w[c + 3], h.w, acc[k]);
      }
    }
#pragma unroll
    for (int k = 0; k < 8; ++k) bufA[(g * 8 + k) * 64 + o] = fmaxf(acc[k], 0.0f);
  }
  __syncthreads();
  {
    const int o = tid & 127, g = tid >> 7;
    float w[64];
    const float* wr = W3 + o * 64;
#pragma unroll
    for (int c = 0; c < 64; ++c) w[c] = wr[c];
    float bias = b3[o];
    float acc[16];
#pragma unroll
    for (int k = 0; k < 16; ++k) acc[k] = bias;
#pragma unroll
    for (int kb = 0; kb < 16; kb += 8) {
#pragma unroll
      for (int c = 0; c < 64; c += 4) {
#pragma unroll
        for (int k = 0; k < 8; ++k) {
          float4 h = *(const float4*)(bufA + (g * 16 + kb + k) * 64 + c);
          acc[kb + k] = fmaf(w[c], h.x, acc[kb + k]);
          acc[kb + k] = fmaf(w[c + 1], h.y, acc[kb + k]);
          acc[kb + k] = fmaf(w[c + 2], h.z, acc[kb + k]);
          acc[kb + k] = fmaf(w[c + 3], h.w, acc[kb + k]);
        }
      }
    }
    float mx = 0.0f;
#pragma unroll
    for (int k = 0; k < 16; ++k) mx = fmaxf(mx, fmaxf(acc[k], 0.0f));
    bufB[g * 128 + o] = mx;
  }
  __syncthreads();
  if (tid < 128) {
    float v = fmaxf(bufB[tid], bufB[128 + tid]);
    outf[((size_t)b * 128 + tid) * NPT + m] = v;
  }
}

extern "C" void kernel_launch(void* const* d_in, const int* in_sizes, int n_in,
                              void* d_out, int out_size, void* d_ws, size_t ws_size,
                              hipStream_t stream) {
  const float* xyz   = (const float*)d_in[0];
  const float* feats = (const float*)d_in[1];
  const float* W1 = (const float*)d_in[2];
  const float* b1 = (const float*)d_in[3];
  const float* W2 = (const float*)d_in[4];
  const float* b2 = (const float*)d_in[5];
  const float* W3 = (const float*)d_in[6];
  const float* b3 = (const float*)d_in[7];
  float* out = (float*)d_out;
  float* newxyz = out;                 // (4,1024,3)
  float* outf = out + NB * NPT * 3;    // (4,128,1024)
  // ws: sorted float4[4*16384] (1MB) | bbox float4[4*512] (32KB) | ballidx (512KB)
  float4* sorted = (float4*)d_ws;
  float4* bbox = sorted + (size_t)NB * NN;
  int* ballidx = (int*)(bbox + (size_t)NB * 2 * NCELL);

  hipLaunchKernelGGL(prep_kernel, dim3(NB), dim3(1024), 0, stream, xyz, sorted, bbox);
  hipLaunchKernelGGL(fps_kernel, dim3(NB), dim3(512), 0, stream, xyz, sorted, bbox, newxyz);
  hipLaunchKernelGGL(ball_kernel, dim3(NB * NPT / 4), dim3(256), 0, stream, xyz, newxyz, ballidx);
  hipLaunchKernelGGL(mlp_kernel, dim3(NB * NPT), dim3(256), 0, stream,
                     xyz, feats, newxyz, ballidx, W1, b1, W2, b2, W3, b3, outf);
}